// Round 6
// baseline (642.029 us; speedup 1.0000x reference)
//
#include <hip/hip_runtime.h>
#include <stdint.h>

#define B_   2
#define S_   1024
#define D_   2048
#define H_   16
#define KV_  4
#define HD_  128
#define NTOK (B_ * S_)        /* 2048 tokens */
#define QD   (H_ * HD_)       /* 2048 */
#define KD   (KV_ * HD_)      /* 512  */

using i32x4  = __attribute__((ext_vector_type(4)))  int;
using i32x16 = __attribute__((ext_vector_type(16))) int;
using f32x4  = __attribute__((ext_vector_type(4)))  float;
using bf16x8 = __attribute__((ext_vector_type(8)))  short;

#define LN1E4_OVER_64 0.14391156831212725f

// ---------------- bf16 helpers ---------------------------------------------
__device__ __forceinline__ float bf2f(uint16_t u) { return __uint_as_float((uint32_t)u << 16); }
__device__ __forceinline__ uint16_t f2bf(float f) {
    uint32_t u = __float_as_uint(f);
    return (uint16_t)((u + 0x7FFFu + ((u >> 16) & 1u)) >> 16);   // RNE
}

// ---------------------------------------------------------------------------
// Per-token joint absmax int8 quantization (dim = 2048 fixed).
// ---------------------------------------------------------------------------
__global__ __launch_bounds__(256)
void act_quant_i8_kernel(const float* __restrict__ xr, const float* __restrict__ xi,
                         int8_t* __restrict__ qr, int8_t* __restrict__ qi,
                         float* __restrict__ invs)
{
    const int tok = blockIdx.x, t = threadIdx.x;
    const float* pr = xr + (size_t)tok * 2048 + t * 8;
    const float* pi = xi + (size_t)tok * 2048 + t * 8;
    float4 r0 = *(const float4*)pr, r1 = *(const float4*)(pr + 4);
    float4 i0 = *(const float4*)pi, i1 = *(const float4*)(pi + 4);
    float am = fmaxf(fmaxf(fmaxf(fabsf(r0.x), fabsf(r0.y)), fmaxf(fabsf(r0.z), fabsf(r0.w))),
                     fmaxf(fmaxf(fabsf(r1.x), fabsf(r1.y)), fmaxf(fabsf(r1.z), fabsf(r1.w))));
    am = fmaxf(am, fmaxf(fmaxf(fmaxf(fabsf(i0.x), fabsf(i0.y)), fmaxf(fabsf(i0.z), fabsf(i0.w))),
                         fmaxf(fmaxf(fabsf(i1.x), fabsf(i1.y)), fmaxf(fabsf(i1.z), fabsf(i1.w)))));
    __shared__ float red[256];
    red[t] = am;
    __syncthreads();
    for (int st = 128; st > 0; st >>= 1) {
        if (t < st) red[t] = fmaxf(red[t], red[t + st]);
        __syncthreads();
    }
    const float s = 127.0f / fmaxf(red[0], 1e-5f);
    if (t == 0) invs[tok] = 1.0f / s;
#define Q8(x) ((uint32_t)(uint8_t)(int8_t)(int)fminf(fmaxf(rintf((x) * s), -128.f), 127.f))
    uint32_t a0 = Q8(r0.x) | (Q8(r0.y) << 8) | (Q8(r0.z) << 16) | (Q8(r0.w) << 24);
    uint32_t a1 = Q8(r1.x) | (Q8(r1.y) << 8) | (Q8(r1.z) << 16) | (Q8(r1.w) << 24);
    uint32_t b0 = Q8(i0.x) | (Q8(i0.y) << 8) | (Q8(i0.z) << 16) | (Q8(i0.w) << 24);
    uint32_t b1 = Q8(i1.x) | (Q8(i1.y) << 8) | (Q8(i1.z) << 16) | (Q8(i1.w) << 24);
#undef Q8
    *(uint32_t*)(qr + (size_t)tok * 2048 + t * 8)     = a0;
    *(uint32_t*)(qr + (size_t)tok * 2048 + t * 8 + 4) = a1;
    *(uint32_t*)(qi + (size_t)tok * 2048 + t * 8)     = b0;
    *(uint32_t*)(qi + (size_t)tok * 2048 + t * 8 + 4) = b1;
}

// ---------------------------------------------------------------------------
// Weight decode + transpose + fused mag reduction.
// ---------------------------------------------------------------------------
__global__ __launch_bounds__(256)
void decode_kernel(const float* __restrict__ wr, const float* __restrict__ wi,
                   int N, int8_t* __restrict__ psr, int8_t* __restrict__ psi,
                   int8_t* __restrict__ pnsi, int n_off, float* __restrict__ mag_out)
{
    __shared__ alignas(16) int8_t tr[3][64][80];
    __shared__ float red[256];
    const int n0 = blockIdx.x * 64, k0 = blockIdx.y * 64;
    float msum = 0.f;
    for (int idx = threadIdx.x; idx < 4096; idx += 256) {
        int j = idx & 63, i = idx >> 6;                 // j = n, i = k
        size_t g = (size_t)(k0 + i) * N + n0 + j;
        float a = wr[g], b = wi[g];
        msum += sqrtf(a * a + b * b);
        int8_t sr, si;
        if (fabsf(a) >= fabsf(b)) {
            sr = (a > 0.f) ? 1 : ((a < 0.f) ? -1 : 0);
            si = 0;
        } else {
            sr = 0;
            si = (b > 0.f) ? 1 : ((b < 0.f) ? -1 : 0);
        }
        tr[0][j][i] = sr;
        tr[1][j][i] = si;
        tr[2][j][i] = (int8_t)(-si);
    }
    red[threadIdx.x] = msum;
    __syncthreads();
    for (int st = 128; st > 0; st >>= 1) {
        if (threadIdx.x < st) red[threadIdx.x] += red[threadIdx.x + st];
        __syncthreads();
    }
    if (threadIdx.x == 0) atomicAdd(mag_out, red[0]);
    int8_t* planes[3] = { psr, psi, pnsi };
    for (int idx = threadIdx.x; idx < 768; idx += 256) {
        int p = idx >> 8, rem = idx & 255, n = rem >> 2, c = rem & 3;
        int4 v = *(const int4*)&tr[p][n][c * 16];
        *(int4*)(planes[p] + (size_t)(n_off + n0 + n) * 2048 + k0 + c * 16) = v;
    }
}

// ---------------------------------------------------------------------------
// int8 MFMA complex GEMM — double-buffered LDS DMA pipeline (raw s_barrier +
// partial vmcnt), XCD-aware block swizzle for L2 locality.
// MODE 0 epilogue: q fp32 planes | K bf16 [b][kv][s][128] | V^T bf16
// [b][kv][d][1024] (transpose fused here — vtrans kernel eliminated).
// ---------------------------------------------------------------------------
__device__ __forceinline__ void async_copy16(const void* g, void* l) {
    __builtin_amdgcn_global_load_lds((const __attribute__((address_space(1))) void*)g,
                                     (__attribute__((address_space(3))) void*)l, 16, 0, 0);
}

template <int MODE>
__global__ __launch_bounds__(256)
void gemm_i8_kernel(const int8_t* __restrict__ axr, const int8_t* __restrict__ axi,
                    const int8_t* __restrict__ bsr, const int8_t* __restrict__ bsi,
                    const int8_t* __restrict__ bnsi,
                    int Nout, const float* __restrict__ invs,
                    const float* __restrict__ mag_sums,
                    float magc0, float magc1, float magc2,
                    float* o_re, float* o_im,
                    uint16_t* kbr, uint16_t* kbi, uint16_t* vtr, uint16_t* vti)
{
    __shared__ alignas(16) int8_t smem[2][5 * 8192];   // 80 KB, 2-stage
    const int tid = threadIdx.x;
    const int wav = tid >> 6, lane = tid & 63;
    // XCD swizzle: block l runs on XCD l&7 (round-robin); give each XCD a
    // column strip so its 4MB L2 keeps the B-planes resident.
    const int l = blockIdx.y * gridDim.x + blockIdx.x;
    const int cpx = gridDim.x >> 3;                    // cols per XCD (3 or 2)
    const int s7 = l >> 3;
    const int tileN = ((l & 7) * cpx + (s7 >> 4)) * 128;
    const int tileM = (s7 & 15) * 128;
    const int wm = wav & 1, wn = wav >> 1;
    const int K = 2048;

    const int8_t* gplane[5] = { axr, axi, bsr, bsi, bnsi };
    const int     rbase[5]  = { tileM, tileM, tileN, tileN, tileN };

    i32x16 acc_re[2][2] = {};
    i32x16 acc_im[2][2] = {};

    auto issue_tile = [&](int k0, int buf) {
#pragma unroll
        for (int i = 0; i < 10; ++i) {
            int q = wav + 4 * i;            // 40 lds-dma per tile, 10 per wave
            int pl = q >> 3, seg = q & 7;
            int c = seg >> 1, m0 = (seg & 1) << 6;
            const int8_t* g = gplane[pl] + (size_t)(rbase[pl] + m0 + lane) * K + k0 + c * 16;
            int8_t* lp = &smem[buf][pl * 8192 + (c * 128 + m0) * 16];
            async_copy16(g, lp);
        }
    };

    issue_tile(0, 0);
    issue_tile(64, 1);

    for (int k = 0; k < 32; ++k) {
        if (k == 31) { asm volatile("s_waitcnt vmcnt(0)" ::: "memory"); }
        else         { asm volatile("s_waitcnt vmcnt(10)" ::: "memory"); }
        asm volatile("s_barrier" ::: "memory");
        const int8_t* sb = smem[k & 1];
#pragma unroll
        for (int s = 0; s < 2; ++s) {
            const int cc = 2 * s + (lane >> 5);
            const int rA = wm * 64 + (lane & 31);
            const int rB = wn * 64 + (lane & 31);
            i32x4 fxr[2], fxi[2], fsr[2], fsi[2], fns[2];
#pragma unroll
            for (int mb = 0; mb < 2; ++mb) {
                int off = (cc * 128 + rA + mb * 32) * 16;
                fxr[mb] = *(const i32x4*)&sb[0 * 8192 + off];
                fxi[mb] = *(const i32x4*)&sb[1 * 8192 + off];
            }
#pragma unroll
            for (int nb = 0; nb < 2; ++nb) {
                int off = (cc * 128 + rB + nb * 32) * 16;
                fsr[nb] = *(const i32x4*)&sb[2 * 8192 + off];
                fsi[nb] = *(const i32x4*)&sb[3 * 8192 + off];
                fns[nb] = *(const i32x4*)&sb[4 * 8192 + off];
            }
#pragma unroll
            for (int mb = 0; mb < 2; ++mb)
#pragma unroll
                for (int nb = 0; nb < 2; ++nb) {
                    acc_re[mb][nb] = __builtin_amdgcn_mfma_i32_32x32x32_i8(fxr[mb], fsr[nb], acc_re[mb][nb], 0, 0, 0);
                    acc_re[mb][nb] = __builtin_amdgcn_mfma_i32_32x32x32_i8(fxi[mb], fns[nb], acc_re[mb][nb], 0, 0, 0);
                    acc_im[mb][nb] = __builtin_amdgcn_mfma_i32_32x32x32_i8(fxr[mb], fsi[nb], acc_im[mb][nb], 0, 0, 0);
                    acc_im[mb][nb] = __builtin_amdgcn_mfma_i32_32x32x32_i8(fxi[mb], fsr[nb], acc_im[mb][nb], 0, 0, 0);
                }
        }
        asm volatile("s_barrier" ::: "memory");       // all reads of buf done
        if (k + 2 < 32) issue_tile((k + 2) * 64, k & 1);
    }

    const int ln31 = lane & 31, lq = lane >> 5;
#pragma unroll
    for (int mb = 0; mb < 2; ++mb) {
#pragma unroll
        for (int nb = 0; nb < 2; ++nb) {
            const int gn = tileN + wn * 64 + nb * 32 + ln31;
            float mag;
            if (MODE == 0)
                mag = (gn < 2048) ? mag_sums[0] * magc0
                    : (gn < 2560) ? mag_sums[1] * magc1
                                  : mag_sums[2] * magc2;
            else
                mag = mag_sums[0] * magc0;
#pragma unroll
            for (int r = 0; r < 16; ++r) {
                const int row = (r & 3) + 8 * (r >> 2) + 4 * lq;
                const int gm = tileM + wm * 64 + mb * 32 + row;
                const float sc = mag * invs[gm];
                const float re = (float)acc_re[mb][nb][r] * sc;
                const float im = (float)acc_im[mb][nb][r] * sc;
                if (MODE == 1) {
                    o_re[(size_t)gm * Nout + gn] = re;
                    o_im[(size_t)gm * Nout + gn] = im;
                } else {
                    const int s = gm & (S_ - 1), bb = gm >> 10;
                    if (gn < 2048) {
                        o_re[(size_t)gm * 2048 + gn] = re;
                        o_im[(size_t)gm * 2048 + gn] = im;
                    } else if (gn < 2560) {
                        int c = gn - 2048, kvh = c >> 7, d = c & 127;
                        size_t off = ((size_t)(bb * KV_ + kvh) * S_ + s) * 128 + d;
                        kbr[off] = f2bf(re);
                        kbi[off] = f2bf(im);
                    } else {
                        int c = gn - 2560, kvh = c >> 7, d = c & 127;
                        size_t off = ((size_t)(bb * KV_ + kvh) * 128 + d) * (size_t)S_ + s;
                        vtr[off] = f2bf(re);      // V^T written directly
                        vti[off] = f2bf(im);
                    }
                }
            }
        }
    }
}

// RoPE in place on K real bf16 plane [b][kv][s][128].
__global__ __launch_bounds__(256)
void rope_k_kernel(uint16_t* __restrict__ kb_re)
{
    int gidx = blockIdx.x * 256 + threadIdx.x;
    int j = gidx & 15, kvh = (gidx >> 4) & 3;
    int rest = gidx >> 6;
    int s = rest & (S_ - 1), b = rest >> 10;
    int d0 = j * 4;
    size_t base = ((size_t)(b * KV_ + kvh) * S_ + s) * 128;
    ushort4 u0 = *(const ushort4*)&kb_re[base + d0];
    ushort4 u1 = *(const ushort4*)&kb_re[base + d0 + 64];
    float rv0[4] = { bf2f(u0.x), bf2f(u0.y), bf2f(u0.z), bf2f(u0.w) };
    float rv1[4] = { bf2f(u1.x), bf2f(u1.y), bf2f(u1.z), bf2f(u1.w) };
    float ro0[4], ro1[4];
#pragma unroll
    for (int t = 0; t < 4; ++t) {
        float f = __expf(-(float)(d0 + t) * LN1E4_OVER_64);
        float sn, c;
        __sincosf((float)s * f, &sn, &c);
        ro0[t] = rv0[t] * c - rv1[t] * sn;
        ro1[t] = rv1[t] * c + rv0[t] * sn;
    }
    *(ushort4*)&kb_re[base + d0]      = (ushort4){ f2bf(ro0[0]), f2bf(ro0[1]), f2bf(ro0[2]), f2bf(ro0[3]) };
    *(ushort4*)&kb_re[base + d0 + 64] = (ushort4){ f2bf(ro1[0]), f2bf(ro1[1]), f2bf(ro1[2]), f2bf(ro1[3]) };
}

// ---------------------------------------------------------------------------
// Barrier-free MFMA flash attention. No K/V LDS staging: B-fragments load
// straight from global (K [pos][d], V^T [d][pos] both match the B-frag
// pattern; served from per-XCD L2, 1 MB per (b,kvh)). Q-RoPE fused in
// registers. Each wave owns 16 q-rows, iterates ONLY its causal range, no
// __syncthreads at all. LDS = 5 KB (per-wave P round-trip only).
// ---------------------------------------------------------------------------
__global__ __launch_bounds__(256)
void attn_mfma_kernel(const float* __restrict__ q_re, const float* __restrict__ q_im,
                      const uint16_t* __restrict__ kb_re, const uint16_t* __restrict__ kb_im,
                      const uint16_t* __restrict__ vt_re, const uint16_t* __restrict__ vt_im,
                      float* __restrict__ o_re, float* __restrict__ o_im)
{
    __shared__ alignas(16) uint16_t sp[4][16][40];    // 80B rows (16B-aligned)

    const int tid = threadIdx.x;
    const int w = tid >> 6, lane = tid & 63;
    const int r16 = lane & 15, q4 = lane >> 4;
    const int qt = gridDim.x - 1 - blockIdx.x;        // heavy blocks first
    const int h = blockIdx.y, b = blockIdx.z;
    const int kvh = h >> 2;
    const int qw0 = qt * 64 + w * 16;
    const int srow = qw0 + r16;

    // ---- Q load (fp32 planes) + fused RoPE on re + bf16 pack ----
    bf16x8 qfr[4], qfi[4];
    {
        const size_t qbase = ((size_t)(b * S_ + srow)) * 2048 + h * 128;
        float fre[4][8];
#pragma unroll
        for (int ks = 0; ks < 4; ++ks) {
            const int col = ks * 32 + q4 * 8;
            float4 a = *(const float4*)&q_re[qbase + col];
            float4 bb4 = *(const float4*)&q_re[qbase + col + 4];
            fre[ks][0] = a.x; fre[ks][1] = a.y; fre[ks][2] = a.z; fre[ks][3] = a.w;
            fre[ks][4] = bb4.x; fre[ks][5] = bb4.y; fre[ks][6] = bb4.z; fre[ks][7] = bb4.w;
            float4 c4 = *(const float4*)&q_im[qbase + col];
            float4 d4 = *(const float4*)&q_im[qbase + col + 4];
            qfi[ks][0] = (short)f2bf(c4.x); qfi[ks][1] = (short)f2bf(c4.y);
            qfi[ks][2] = (short)f2bf(c4.z); qfi[ks][3] = (short)f2bf(c4.w);
            qfi[ks][4] = (short)f2bf(d4.x); qfi[ks][5] = (short)f2bf(d4.y);
            qfi[ks][6] = (short)f2bf(d4.z); qfi[ks][7] = (short)f2bf(d4.w);
        }
#pragma unroll
        for (int kp = 0; kp < 2; ++kp)
#pragma unroll
            for (int j = 0; j < 8; ++j) {
                const int d = kp * 32 + q4 * 8 + j;   // 0..63; partner d+64
                float f = __expf(-(float)d * LN1E4_OVER_64);
                float sn, cc;
                __sincosf((float)srow * f, &sn, &cc);
                float v0 = fre[kp][j], v1 = fre[kp + 2][j];
                fre[kp][j]     = v0 * cc - v1 * sn;
                fre[kp + 2][j] = v1 * cc + v0 * sn;
            }
#pragma unroll
        for (int ks = 0; ks < 4; ++ks)
#pragma unroll
            for (int j = 0; j < 8; ++j)
                qfr[ks][j] = (short)f2bf(fre[ks][j]);
    }

    f32x4 oa[2][8] = {};
    float m_r[4] = { -3e38f, -3e38f, -3e38f, -3e38f };
    float l_r[4] = { 0.f, 0.f, 0.f, 0.f };

    const size_t kgbase = (size_t)(b * KV_ + kvh) * S_ * 128;
    const size_t vgbase = (size_t)(b * KV_ + kvh) * 128 * (size_t)S_;

    for (int c0 = 0; c0 < qw0 + 16; c0 += 32) {
        // ---- scores: K B-frags straight from global ----
        f32x4 sc[2] = {};
#pragma unroll
        for (int cblk = 0; cblk < 2; ++cblk) {
            const size_t krow = kgbase + (size_t)(c0 + cblk * 16 + r16) * 128 + q4 * 8;
#pragma unroll
            for (int ks = 0; ks < 4; ++ks) {
                bf16x8 kr = *(const bf16x8*)&kb_re[krow + ks * 32];
                bf16x8 ki = *(const bf16x8*)&kb_im[krow + ks * 32];
                sc[cblk] = __builtin_amdgcn_mfma_f32_16x16x32_bf16(qfr[ks], kr, sc[cblk], 0, 0, 0);
                sc[cblk] = __builtin_amdgcn_mfma_f32_16x16x32_bf16(qfi[ks], ki, sc[cblk], 0, 0, 0);
            }
        }
        // scale + causal mask (C-layout: row=q4*4+reg, col=r16)
#pragma unroll
        for (int cblk = 0; cblk < 2; ++cblk)
#pragma unroll
            for (int reg = 0; reg < 4; ++reg) {
                float sval = sc[cblk][reg] * 0.08838834764831845f;
                const int rowg = qw0 + q4 * 4 + reg;
                const int colg = c0 + cblk * 16 + r16;
                if (colg > rowg) sval = -3e38f;
                sc[cblk][reg] = sval;
            }
        // ---- online softmax (16-lane shuffle groups) ----
        float al[4];
#pragma unroll
        for (int reg = 0; reg < 4; ++reg) {
            float mx = fmaxf(sc[0][reg], sc[1][reg]);
#pragma unroll
            for (int msk = 1; msk < 16; msk <<= 1) mx = fmaxf(mx, __shfl_xor(mx, msk));
            const float mn = fmaxf(m_r[reg], mx);
            al[reg] = __expf(m_r[reg] - mn);
            const float p0 = __expf(sc[0][reg] - mn);
            const float p1 = __expf(sc[1][reg] - mn);
            sc[0][reg] = p0; sc[1][reg] = p1;
            float rs = p0 + p1;
#pragma unroll
            for (int msk = 1; msk < 16; msk <<= 1) rs += __shfl_xor(rs, msk);
            l_r[reg] = l_r[reg] * al[reg] + rs;
            m_r[reg] = mn;
        }
        // ---- P: C-layout -> own LDS region -> A-layout (wave-local) ----
#pragma unroll
        for (int cblk = 0; cblk < 2; ++cblk)
#pragma unroll
            for (int reg = 0; reg < 4; ++reg)
                sp[w][q4 * 4 + reg][cblk * 16 + r16] = f2bf(sc[cblk][reg]);
        // ---- rescale O ----
#pragma unroll
        for (int dblk = 0; dblk < 8; ++dblk)
#pragma unroll
            for (int reg = 0; reg < 4; ++reg) {
                oa[0][dblk][reg] *= al[reg];
                oa[1][dblk][reg] *= al[reg];
            }
        bf16x8 pf = *(const bf16x8*)&sp[w][r16][q4 * 8];
        // ---- PV: V^T B-frags straight from global ----
#pragma unroll
        for (int dblk = 0; dblk < 8; ++dblk) {
            const size_t vrow = vgbase + (size_t)(dblk * 16 + r16) * S_ + c0 + q4 * 8;
            bf16x8 vr = *(const bf16x8*)&vt_re[vrow];
            bf16x8 vi = *(const bf16x8*)&vt_im[vrow];
            oa[0][dblk] = __builtin_amdgcn_mfma_f32_16x16x32_bf16(pf, vr, oa[0][dblk], 0, 0, 0);
            oa[1][dblk] = __builtin_amdgcn_mfma_f32_16x16x32_bf16(pf, vi, oa[1][dblk], 0, 0, 0);
        }
    }

    float inv[4];
#pragma unroll
    for (int reg = 0; reg < 4; ++reg) inv[reg] = 1.f / l_r[reg];
#pragma unroll
    for (int dblk = 0; dblk < 8; ++dblk) {
        const int col = h * 128 + dblk * 16 + r16;
#pragma unroll
        for (int reg = 0; reg < 4; ++reg) {
            const size_t tok = (size_t)b * S_ + qw0 + q4 * 4 + reg;
            o_re[tok * 2048 + col] = oa[0][dblk][reg] * inv[reg];
            o_im[tok * 2048 + col] = oa[1][dblk][reg] * inv[reg];
        }
    }
}

// ---------------------------------------------------------------------------
extern "C" void kernel_launch(void* const* d_in, const int* in_sizes, int n_in,
                              void* d_out, int out_size, void* d_ws, size_t ws_size,
                              hipStream_t stream)
{
    const float* hr    = (const float*)d_in[0];
    const float* hi    = (const float*)d_in[1];
    const float* wq_re = (const float*)d_in[2];
    const float* wq_im = (const float*)d_in[3];
    const float* wk_re = (const float*)d_in[4];
    const float* wk_im = (const float*)d_in[5];
    const float* wv_re = (const float*)d_in[6];
    const float* wv_im = (const float*)d_in[7];
    const float* wo_re = (const float*)d_in[8];
    const float* wo_im = (const float*)d_in[9];
    float* out = (float*)d_out;
    char*  base = (char*)d_ws;

    const size_t MB4  = (size_t)2048 * 2048;
    const size_t QKVP = (size_t)3072 * 2048;
    const size_t KVE  = (size_t)B_ * KV_ * S_ * 128;

    float*   mags   = (float*)(base);
    float*   invs1  = (float*)(base + 1024);
    float*   invs2  = (float*)(base + 9216);
    int8_t*  xr_q   = (int8_t*)(base + 32768);
    int8_t*  xi_q   = xr_q + MB4;
    int8_t*  qkv_sr = xi_q + MB4;
    int8_t*  qkv_si = qkv_sr + QKVP;
    int8_t*  qkv_ns = qkv_si + QKVP;
    int8_t*  wo_sr  = qkv_ns + QKVP;
    int8_t*  wo_si  = wo_sr + MB4;
    int8_t*  wo_ns  = wo_si + MB4;
    float*   q_re   = (float*)(wo_ns + MB4);        // fp32 [tok][2048]; reused as o
    float*   q_im   = q_re + MB4;
    uint16_t* kb_re = (uint16_t*)(q_im + MB4);      // bf16 [b][kv][s][128]
    uint16_t* kb_im = kb_re + KVE;
    uint16_t* vt_re = kb_im + KVE;                  // bf16 [b][kv][d][1024]
    uint16_t* vt_im = vt_re + KVE;

    hipMemsetAsync(mags, 0, 16, stream);

    decode_kernel<<<dim3(32, 32), 256, 0, stream>>>(wq_re, wq_im, 2048, qkv_sr, qkv_si, qkv_ns, 0,    mags + 0);
    decode_kernel<<<dim3(8, 32),  256, 0, stream>>>(wk_re, wk_im, 512,  qkv_sr, qkv_si, qkv_ns, 2048, mags + 1);
    decode_kernel<<<dim3(8, 32),  256, 0, stream>>>(wv_re, wv_im, 512,  qkv_sr, qkv_si, qkv_ns, 2560, mags + 2);
    decode_kernel<<<dim3(32, 32), 256, 0, stream>>>(wo_re, wo_im, 2048, wo_sr, wo_si, wo_ns, 0,       mags + 3);

    act_quant_i8_kernel<<<NTOK, 256, 0, stream>>>(hr, hi, xr_q, xi_q, invs1);

    gemm_i8_kernel<0><<<dim3(24, 16), 256, 0, stream>>>(
        xr_q, xi_q, qkv_sr, qkv_si, qkv_ns, 0, invs1, mags,
        1.0f / (float)((size_t)D_ * QD), 1.0f / (float)((size_t)D_ * KD), 1.0f / (float)((size_t)D_ * KD),
        q_re, q_im, kb_re, kb_im, vt_re, vt_im);

    rope_k_kernel<<<NTOK * KV_ * 16 / 256, 256, 0, stream>>>(kb_re);

    attn_mfma_kernel<<<dim3(S_ / 64, H_, B_), 256, 0, stream>>>(
        q_re, q_im, kb_re, kb_im, vt_re, vt_im, q_re, q_im);

    act_quant_i8_kernel<<<NTOK, 256, 0, stream>>>(q_re, q_im, xr_q, xi_q, invs2);

    gemm_i8_kernel<1><<<dim3(16, 16), 256, 0, stream>>>(
        xr_q, xi_q, wo_sr, wo_si, wo_ns, 2048, invs2, mags + 3,
        1.0f / (float)((size_t)QD * D_), 0.f, 0.f,
        out, out + MB4, nullptr, nullptr, nullptr, nullptr);
}